// Round 20
// baseline (450.677 us; speedup 1.0000x reference)
//
#include <hip/hip_runtime.h>
#include <stdint.h>
#include <stddef.h>

#define DEV static __device__ __forceinline__

typedef __attribute__((ext_vector_type(8))) short bf16x8;
typedef __attribute__((ext_vector_type(4))) float f32x4;
typedef __attribute__((ext_vector_type(4))) int i32x4;

// ---------- small helpers ----------
DEV float bf2f(unsigned short u){ union{unsigned int i; float f;} v; v.i = ((unsigned int)u)<<16; return v.f; }
DEV unsigned short f2bf(float f){ union{float f; unsigned int i;} v; v.f=f; unsigned int i=v.i;
  return (unsigned short)((i + 0x7FFFu + ((i>>16)&1u)) >> 16); }
DEV unsigned int fenc(float x){ unsigned int i = __float_as_uint(x); return (i & 0x80000000u) ? ~i : (i | 0x80000000u); }
DEV float fdec(unsigned int e){ unsigned int i = (e & 0x80000000u) ? (e & 0x7FFFFFFFu) : ~e; return __uint_as_float(i); }

DEV float waveSum(float s){
  for (int m=32;m;m>>=1) s += __shfl_xor(s, m, 64);
  return s;
}

DEV float blockSum(float v, float* red){
  int t = threadIdx.x;
  red[t] = v; __syncthreads();
  for (int k=128;k>0;k>>=1){ if (t<k) red[t] += red[t+k]; __syncthreads(); }
  float r = red[0]; __syncthreads();
  return r;
}

// async global->LDS, 16B per lane; lds base wave-uniform, dest = base + lane*16
DEV void gl16(const void* g, void* lds){
  __builtin_amdgcn_global_load_lds(
      (const __attribute__((address_space(1))) void*)g,
      (__attribute__((address_space(3))) void*)lds, 16, 0, 0);
}

// XLA ErfInv32 (Giles polynomial, log1p variant)
DEV float erfinv_f(float x){
  float w = -log1pf(-__fmul_rn(x,x));
  float p;
  if (w < 5.0f){
    w = w - 2.5f;
    p = 2.81022636e-08f;
    p = 3.43273939e-07f + p*w;
    p = -3.5233877e-06f + p*w;
    p = -4.39150654e-06f + p*w;
    p = 0.00021858087f + p*w;
    p = -0.00125372503f + p*w;
    p = -0.00417768164f + p*w;
    p = 0.246640727f + p*w;
    p = 1.50140941f + p*w;
  } else {
    w = sqrtf(w) - 3.0f;
    p = -0.000200214257f;
    p = 0.000100950558f + p*w;
    p = 0.00134934322f + p*w;
    p = -0.00367342844f + p*w;
    p = 0.00573950773f + p*w;
    p = -0.0076224613f + p*w;
    p = 0.00943887047f + p*w;
    p = 1.00167406f + p*w;
    p = 2.83297682f + p*w;
  }
  return p*x;
}

// ---------- constants ----------
#define BN_TOT 32768
#define DIM 768
#define NCLS 201
#define KP 5
#define CKPAD 1024
#define NSPLIT_G 16       // K-splits per chain (2 chains -> 32 Gpart slices)
#define GSPLIT 32
#define PSPLIT 8
#define NBLK_G 672        // G12 blocks (2 chains x 336)

// ---------- kernels ----------

// fused setup: init accumulators + labels canonicalize + v0 + proto-normalize
__global__ void k_setup(unsigned int* ipl_enc, int* cnt, int* cur, int* present,
                        unsigned int* minmax, float* meansum,
                        const int* __restrict__ raw, int* __restrict__ lab,
                        float* __restrict__ v,
                        const float* __restrict__ protos, unsigned short* __restrict__ protn,
                        int* __restrict__ dcnt){
  int i = blockIdx.x*256 + threadIdx.x;   // exactly 32768 threads
  ipl_enc[i] = 0u;
  if (i < NCLS){ cnt[i]=0; cur[i]=0; present[i]=0; }
  if (i < DIM) meansum[i] = 0.f;
  if (i == 0){
    minmax[0]=0xFFFFFFFFu; minmax[1]=0u;
    dcnt[0] = 0;
    bool is64 = true;
    for (int j=0;j<8;j++){
      int lo = raw[2*j], hi = raw[2*j+1];
      if (hi != 0 || lo < 0 || lo >= NCLS-1){ is64 = false; break; }
    }
    for (int j=0;j<32;j++) lab[j] = is64 ? raw[2*j] : raw[j];
  }
  if (i < DIM){
    unsigned int ks[3] = {0u, 1u, 0x1BD11BDBu};
    const int rot0[4] = {13,15,26,6};
    const int rot1[4] = {17,29,16,24};
    unsigned int x0 = 0u, x1 = (unsigned int)i;
    x0 += ks[0]; x1 += ks[1];
    #pragma unroll
    for (int g=0; g<5; g++){
      const int* rr = (g&1) ? rot1 : rot0;
      #pragma unroll
      for (int j=0;j<4;j++){
        x0 += x1;
        x1 = (x1 << rr[j]) | (x1 >> (32-rr[j]));
        x1 ^= x0;
      }
      x0 += ks[(g+1)%3];
      x1 += ks[(g+2)%3] + (unsigned int)(g+1);
    }
    unsigned int b = x0 ^ x1;
    const float lo = __uint_as_float(0xBF7FFFFFu);
    const float sq2 = __uint_as_float(0x3FB504F3u);
    float f = __uint_as_float((b>>9) | 0x3F800000u) - 1.0f;
    float uu = __fadd_rn(__fmul_rn(f, 2.0f), lo);
    uu = fmaxf(lo, uu);
    v[i] = sq2 * erfinv_f(uu);
  }
  // proto rows: 8 per block, 2 rows per wave
  int l = threadIdx.x & 63;
  #pragma unroll
  for (int rr=0; rr<2; rr++){
    int row = blockIdx.x*8 + (threadIdx.x>>6)*2 + rr;
    if (row >= NCLS*KP){
      for (int j=0;j<12;j++) protn[(size_t)row*DIM + l + j*64] = 0;
    } else {
      const float* p = protos + (size_t)row*DIM;
      float x[12]; float s = 0.f;
      for (int j=0;j<12;j++){ x[j] = p[l + j*64]; s += x[j]*x[j]; }
      s = waveSum(s);
      float inv = 1.0f / fmaxf(sqrtf(s), 1e-12f);
      for (int j=0;j<12;j++) protn[(size_t)row*DIM + l + j*64] = f2bf(x[j]*inv);
    }
  }
}

// FUSED prep: single pass over X producing ptn, q1T/q2T, meansum, AND
// q_all[n][k] = exp(20 * <ptn[n], protn[label(n),k]>)  (hoists k_qlog's work
// out of the serial tail; defined for every row, fg rows use it later).
__global__ __launch_bounds__(256) void k_prep(const float* __restrict__ X,
                                              unsigned short* __restrict__ ptn,
                                              signed char* __restrict__ q1T,
                                              signed char* __restrict__ q2T,
                                              float* __restrict__ meansum,
                                              const unsigned short* __restrict__ protn,
                                              const int* __restrict__ raw,
                                              float* __restrict__ q_all){
  __shared__ float tile[16][DIM];
  int bid = blockIdx.x;                 // 2048 blocks
  int xcd = bid & 7, j = bid >> 3;      // j in 0..255
  int n0 = xcd*4096 + j*16;
  int t = threadIdx.x;
  {
    const float4* src = (const float4*)(X + (size_t)n0*DIM);
    float4* dst = (float4*)&tile[0][0];
    #pragma unroll
    for (int i=0;i<12;i++) dst[t + i*256] = src[t + i*256];
  }
  // own-image label (canonicalize int64/int32 per block; uniform, cheap)
  bool is64 = true;
  #pragma unroll
  for (int jj=0;jj<8;jj++){
    int lo = raw[2*jj], hi = raw[2*jj+1];
    if (hi != 0 || lo < 0 || lo >= NCLS-1){ is64 = false; break; }
  }
  int img = n0 >> 10;
  int lab = is64 ? raw[2*img] : raw[img];
  __syncthreads();
  int w = t>>6, l = t&63;
  #pragma unroll
  for (int rr=0; rr<4; rr++){
    int r = w*4 + rr;
    const float4* xr = (const float4*)&tile[r][0];
    float4 x4[3]; float s = 0.f;
    #pragma unroll
    for (int jj=0;jj<3;jj++){
      x4[jj] = xr[l + jj*64];
      s += x4[jj].x*x4[jj].x + x4[jj].y*x4[jj].y + x4[jj].z*x4[jj].z + x4[jj].w*x4[jj].w;
    }
    s = waveSum(s);
    float inv = 1.0f / fmaxf(sqrtf(s), 1e-12f);
    float xb[12];
    #pragma unroll
    for (int jj=0;jj<3;jj++){
      ushort4 o;
      o.x = f2bf(x4[jj].x*inv); o.y = f2bf(x4[jj].y*inv);
      o.z = f2bf(x4[jj].z*inv); o.w = f2bf(x4[jj].w*inv);
      *(ushort4*)&ptn[(size_t)(n0+r)*DIM + 4*(l + jj*64)] = o;
      xb[jj*4+0] = bf2f(o.x); xb[jj*4+1] = bf2f(o.y);
      xb[jj*4+2] = bf2f(o.z); xb[jj*4+3] = bf2f(o.w);
    }
    // q_all: 5 own-label proto dots (bf16-rounded operands, wave reduce)
    #pragma unroll
    for (int k=0;k<KP;k++){
      const ushort4* wv4 = (const ushort4*)&protn[(size_t)(lab*KP + k)*DIM];
      float sd = 0.f;
      #pragma unroll
      for (int jj=0;jj<3;jj++){
        ushort4 wv = wv4[l + jj*64];
        sd += xb[jj*4+0]*bf2f(wv.x) + xb[jj*4+1]*bf2f(wv.y)
            + xb[jj*4+2]*bf2f(wv.z) + xb[jj*4+3]*bf2f(wv.w);
      }
      sd = waveSum(sd);
      if (l==0) q_all[(size_t)(n0+r)*KP + k] = expf(sd*20.0f);
    }
  }
  #pragma unroll
  for (int cc=0; cc<3; cc++){
    int c = t + cc*256;
    unsigned int u1[4], u2[4];
    #pragma unroll
    for (int g=0; g<4; g++){
      unsigned int p1 = 0, p2 = 0;
      #pragma unroll
      for (int k=0;k<4;k++){
        float xx = tile[g*4+k][c];
        int v1 = (int)rintf(xx*16.0f);
        v1 = max(-127, min(127, v1));
        float r2 = xx - (float)v1*(1.0f/16.0f);
        int v2 = (int)rintf(r2*2048.0f);
        v2 = max(-127, min(127, v2));
        p1 |= ((unsigned int)(v1 & 0xff)) << (8*k);
        p2 |= ((unsigned int)(v2 & 0xff)) << (8*k);
      }
      u1[g] = p1; u2[g] = p2;
    }
    uint4 a; a.x=u1[0]; a.y=u1[1]; a.z=u1[2]; a.w=u1[3];
    uint4 b; b.x=u2[0]; b.y=u2[1]; b.z=u2[2]; b.w=u2[3];
    *(uint4*)&q1T[(size_t)c*BN_TOT + n0] = a;
    *(uint4*)&q2T[(size_t)c*BN_TOT + n0] = b;
    float s = 0.f;
    #pragma unroll
    for (int r=0;r<16;r++) s += tile[r][c];
    atomicAdd(&meansum[c], s);
  }
}

// decode (ib,jb) from upper-tri pair index (128-tiles, 6x6) + XCD-grouped split
DEV void g_coords(int b, int& s, int& ib, int& jb){
  int xcd = b & 7, q = b >> 3;            // per chain: 336 blocks, q in 0..41
  s = xcd + 8*(q/21);                     // K-split 0..15 -> xcd s%8 (L2 reuse)
  int p = q % 21;
  ib = 0; int rem = p;
  while (rem >= 6 - ib){ rem -= 6 - ib; ib++; }
  jb = ib + rem;
}

// MEGA dispatch: three independent GEMM populations co-resident (r17 proven).
__global__ __launch_bounds__(256) void k_mega(const signed char* __restrict__ q1T,
                                              const signed char* __restrict__ q2T,
                                              float* __restrict__ Gpart,
                                              const unsigned short* __restrict__ A,
                                              const unsigned short* __restrict__ Bt,
                                              unsigned int* __restrict__ ipl_enc){
  __shared__ __align__(16) signed char LB[32768];
  __shared__ float red[2][2][64];
  int bid = blockIdx.x;
  int t = threadIdx.x, w = t>>6, l = t&63;
  int wr = w>>1, wc = w&1;

  if (bid < NBLK_G){
    int chain2 = (bid >= 21*NSPLIT_G);
    int s, ib, jb; g_coords(chain2 ? bid - 21*NSPLIT_G : bid, s, ib, jb);
    size_t baseA = (size_t)(ib*128)*BN_TOT;
    size_t baseB = (size_t)(jb*128)*BN_TOT;

    i32x4 acc[4][4];
    #pragma unroll
    for (int m=0;m<4;m++)
      #pragma unroll
      for (int n=0;n<4;n++){ acc[m][n][0]=0; acc[m][n][1]=0; acc[m][n][2]=0; acc[m][n][3]=0; }

    float scale;
    if (!chain2){
      signed char* A1 = LB;
      signed char* B1 = LB + 16384;
      int gu = (l&7) ^ ((l>>3)&7);
      size_t lane_off = (size_t)(l>>3)*BN_TOT + (size_t)gu*16;
      for (int kt=0; kt<16; kt++){
        size_t k0 = (size_t)s*2048 + (size_t)kt*128;
        __syncthreads();
        #pragma unroll
        for (int ci=0; ci<4; ci++){
          int rg = w + ci*4;
          size_t roff = (size_t)(rg*8)*BN_TOT + k0 + lane_off;
          gl16(q1T + baseA + roff, A1 + rg*1024);
          gl16(q1T + baseB + roff, B1 + rg*1024);
        }
        __syncthreads();
        #pragma unroll
        for (int kk=0; kk<2; kk++){
          int physb = (((kk*4) + (l>>4)) ^ (l&7))*16;
          i32x4 b1[4];
          #pragma unroll
          for (int n=0;n<4;n++) b1[n] = *(const i32x4*)&B1[(wc*64 + n*16 + (l&15))*128 + physb];
          #pragma unroll
          for (int m=0;m<4;m++){
            i32x4 a1 = *(const i32x4*)&A1[(wr*64 + m*16 + (l&15))*128 + physb];
            #pragma unroll
            for (int n=0;n<4;n++)
              acc[m][n] = __builtin_amdgcn_mfma_i32_16x16x64_i8(a1, b1[n], acc[m][n], 0,0,0);
          }
        }
      }
      scale = 1.0f/256.0f;
    } else {
      signed char* A1 = LB;
      signed char* A2 = LB + 8192;
      signed char* B1 = LB + 16384;
      signed char* B2 = LB + 24576;
      int gu = (l&3) ^ ((l>>2)&3) ^ (l>>4);
      size_t lane_off = (size_t)(l>>2)*BN_TOT + (size_t)gu*16;
      int physc = (l>>4) ^ (l&3) ^ ((l>>2)&3);
      int rdA = (wr*64 + (l&15))*64 + physc*16;
      int rdB = (wc*64 + (l&15))*64 + physc*16;
      for (int kt=0; kt<32; kt++){
        size_t k0 = (size_t)s*2048 + (size_t)kt*64;
        __syncthreads();
        #pragma unroll
        for (int ci=0; ci<2; ci++){
          int c = w + ci*4;
          size_t roff = (size_t)(c*16)*BN_TOT + k0 + lane_off;
          gl16(q1T + baseA + roff, A1 + c*1024);
          gl16(q2T + baseA + roff, A2 + c*1024);
          gl16(q1T + baseB + roff, B1 + c*1024);
          gl16(q2T + baseB + roff, B2 + c*1024);
        }
        __syncthreads();
        i32x4 b1[4], b2[4];
        #pragma unroll
        for (int n=0;n<4;n++){
          b1[n] = *(const i32x4*)&B1[rdB + n*1024];
          b2[n] = *(const i32x4*)&B2[rdB + n*1024];
        }
        #pragma unroll
        for (int m=0;m<4;m++){
          i32x4 a1 = *(const i32x4*)&A1[rdA + m*1024];
          i32x4 a2 = *(const i32x4*)&A2[rdA + m*1024];
          #pragma unroll
          for (int n=0;n<4;n++){
            acc[m][n] = __builtin_amdgcn_mfma_i32_16x16x64_i8(a1, b2[n], acc[m][n], 0,0,0);
            acc[m][n] = __builtin_amdgcn_mfma_i32_16x16x64_i8(a2, b1[n], acc[m][n], 0,0,0);
          }
        }
      }
      scale = 1.0f/32768.0f;
    }

    int slice = chain2 ? (NSPLIT_G + s) : s;
    float* out = Gpart + (size_t)slice*DIM*DIM;
    #pragma unroll
    for (int m=0;m<4;m++)
      #pragma unroll
      for (int n=0;n<4;n++)
        #pragma unroll
        for (int r=0;r<4;r++){
          int row = ib*128 + wr*64 + m*16 + (l>>4)*4 + r;
          int col = jb*128 + wc*64 + n*16 + (l&15);
          float val = (float)acc[m][n][r]*scale;
          out[(size_t)row*DIM + col] = val;
          if (ib != jb) out[(size_t)col*DIM + row] = val;
        }
  } else {
    unsigned short* As = (unsigned short*)LB;          // 16KB
    unsigned short* Bs = (unsigned short*)(LB + 16384);
    int flat = bid - NBLK_G;                           // 0..2047
    int xcd = flat & 7, j = flat >> 3;
    int mb = xcd*32 + (j>>3);
    int nb = j & 7;

    int gu = (l&7) ^ ((l>>3)&7);
    size_t lane_off = (size_t)(l>>3)*DIM + (size_t)gu*8;    // shorts
    size_t baseA = (size_t)(mb*128)*DIM;
    size_t baseB = (size_t)(nb*128)*DIM;

    f32x4 acc[4][4];
    #pragma unroll
    for (int m=0;m<4;m++)
      #pragma unroll
      for (int n=0;n<4;n++){ acc[m][n][0]=0.f; acc[m][n][1]=0.f; acc[m][n][2]=0.f; acc[m][n][3]=0.f; }

    for (int kt=0; kt<12; kt++){
      size_t k0 = (size_t)kt*64;
      __syncthreads();
      #pragma unroll
      for (int ci=0; ci<4; ci++){
        int rg = w + ci*4;
        size_t roff = (size_t)(rg*8)*DIM + k0 + lane_off;
        gl16(A + baseA + roff, &As[rg*512]);
        gl16(Bt + baseB + roff, &Bs[rg*512]);
      }
      __syncthreads();
      #pragma unroll
      for (int kk=0; kk<2; kk++){
        int physb = (((kk*4) + (l>>4)) ^ (l&7))*8;
        bf16x8 a[4], b[4];
        #pragma unroll
        for (int m=0;m<4;m++) a[m] = *(const bf16x8*)&As[(wr*64 + m*16 + (l&15))*64 + physb];
        #pragma unroll
        for (int n=0;n<4;n++) b[n] = *(const bf16x8*)&Bs[(wc*64 + n*16 + (l&15))*64 + physb];
        #pragma unroll
        for (int m=0;m<4;m++)
          #pragma unroll
          for (int n=0;n<4;n++)
            acc[m][n] = __builtin_amdgcn_mfma_f32_16x16x32_bf16(a[m], b[n], acc[m][n], 0,0,0);
      }
    }
    float vmax[4];
    #pragma unroll
    for (int n=0;n<4;n++){
      float v = -1e30f;
      #pragma unroll
      for (int m=0;m<4;m++)
        #pragma unroll
        for (int r=0;r<4;r++) v = fmaxf(v, acc[m][n][r]);
      v = fmaxf(v, __shfl_xor(v, 16, 64));
      v = fmaxf(v, __shfl_xor(v, 32, 64));
      vmax[n] = v;
    }
    __syncthreads();
    if (l < 16){
      #pragma unroll
      for (int n=0;n<4;n++) red[wc][wr][n*16 + l] = vmax[n];
    }
    __syncthreads();
    if (t < 128){
      int wcc = t>>6, col = t&63;
      float v = fmaxf(red[wcc][0][col], red[wcc][1][col]);
      int gcol = nb*128 + wcc*64 + col;
      if (gcol < NCLS*KP){
        int b = (mb*128) >> 10;
        atomicMax(&ipl_enc[b*CKPAD + gcol], fenc(v));
      }
    }
  }
}

// G' = sum(Gpart slices)/N - mu mu^T  (float4; 32 slices)
__global__ void k_gfix(const float* __restrict__ Gpart, const float* __restrict__ meansum,
                       float* __restrict__ G){
  int i4 = blockIdx.x*256 + threadIdx.x;   // < 147456
  int i = i4*4;
  int r = i/DIM, c = i%DIM;
  float4 s = make_float4(0.f,0.f,0.f,0.f);
  for (int p=0;p<GSPLIT;p++){
    float4 g = *(const float4*)&Gpart[(size_t)p*DIM*DIM + i];
    s.x += g.x; s.y += g.y; s.z += g.z; s.w += g.w;
  }
  const float invN = 1.0f/32768.0f;
  float mr = meansum[r]*invN;
  float4 mc = *(const float4*)&meansum[c];
  float4 o;
  o.x = s.x*invN - mr*mc.x*invN;
  o.y = s.y*invN - mr*mc.y*invN;
  o.z = s.z*invN - mr*mc.z*invN;
  o.w = s.w*invN - mr*mc.w*invN;
  *(float4*)&G[i] = o;
}

// v_out = G * v_in   (one wave per row)
__global__ void k_mv(const float* __restrict__ G, const float* __restrict__ vin,
                     float* __restrict__ vout){
  __shared__ float vs[DIM];
  int t = threadIdx.x;
  for (int i=t;i<DIM;i+=256) vs[i] = vin[i];
  __syncthreads();
  int row = blockIdx.x*4 + (t>>6), l = t&63;
  const float* g = G + (size_t)row*DIM;
  float s = 0.f;
  for (int j=0;j<12;j++) s += g[l + j*64]*vs[l + j*64];
  s = waveSum(s);
  if (l==0) vout[row] = s;
}

// u[row] = X[row,:].v - mu.v ; per-block mu.v; fused global min/max.
__global__ void k_u(const float* __restrict__ X, const float* __restrict__ v,
                    const float* __restrict__ meansum,
                    float* __restrict__ u, unsigned int* __restrict__ minmax){
  __shared__ float vs[DIM];
  __shared__ float red[256];
  __shared__ float smn[4], smx[4];
  int t = threadIdx.x;
  for (int i=t;i<DIM;i+=256) vs[i] = v[i];
  __syncthreads();
  float ps = 0.f;
  for (int i=t;i<DIM;i+=256) ps += meansum[i]*(1.0f/32768.0f)*vs[i];
  float scal = blockSum(ps, red);
  int w = t>>6, l = t&63;
  float mn = 1e30f, mx = -1e30f;
  #pragma unroll
  for (int rr=0; rr<4; rr++){
    int row = blockIdx.x*16 + w*4 + rr;
    const float4* xr = (const float4*)(X + (size_t)row*DIM);
    float s = 0.f;
    #pragma unroll
    for (int j=0;j<3;j++){
      float4 x4 = xr[l + j*64];
      int base = 4*(l + j*64);
      s += x4.x*vs[base] + x4.y*vs[base+1] + x4.z*vs[base+2] + x4.w*vs[base+3];
    }
    s = waveSum(s);
    if (l==0){
      float val = s - scal;
      u[row] = val;
      mn = fminf(mn, val); mx = fmaxf(mx, val);
    }
  }
  if (l==0){ smn[w]=mn; smx[w]=mx; }
  __syncthreads();
  if (t==0){
    for (int k=1;k<4;k++){ mn = fminf(mn, smn[k]); mx = fmaxf(mx, smx[k]); }
    atomicMin(&minmax[0], fenc(mn));
    atomicMax(&minmax[1], fenc(mx));
  }
}

// patch labels + per-class counts + (last block) prefix offsets + present bitmap
__global__ void k_pl(const float* __restrict__ u, const int* __restrict__ labels,
                     const unsigned int* __restrict__ minmax, int* __restrict__ pl,
                     int* __restrict__ cnt, int* __restrict__ offs,
                     int* __restrict__ present, int* __restrict__ dcnt){
  int n = blockIdx.x*256 + threadIdx.x;
  int t = threadIdx.x;
  float umin = fdec(minmax[0]), umax = fdec(minmax[1]);
  float us = (u[n]-umin)/(umax-umin);
  int c = (us < 0.5f) ? labels[n>>10] : (NCLS-1);
  pl[n] = c;
  if (c < NCLS-1) atomicAdd(&cnt[c], 1);
  __threadfence();
  __shared__ int lastblk;
  if (t == 0) lastblk = (atomicAdd(dcnt, 1) == 127) ? 1 : 0;
  __syncthreads();
  if (lastblk){
    __shared__ int sc[256];
    sc[t] = (t < NCLS-1) ? atomicAdd(&cnt[t], 0) : 0;
    __syncthreads();
    for (int d=1; d<256; d<<=1){
      int v = (t >= d) ? sc[t-d] : 0;
      __syncthreads();
      sc[t] += v;
      __syncthreads();
    }
    if (t < NCLS) offs[t] = (t == 0) ? 0 : sc[t-1];
    if (t < 32) atomicOr(&present[labels[t]], 1);
  }
}

__global__ void k_scatter(const int* __restrict__ pl, const int* __restrict__ offs,
                          int* __restrict__ cur, int* __restrict__ idx){
  int n = blockIdx.x*256 + threadIdx.x;
  int c = pl[n];
  if (c < NCLS-1){
    int p = offs[c] + atomicAdd(&cur[c], 1);
    idx[p] = n;
  }
}

// per-class sinkhorn on its sorted segment; prologue gathers q0 from q_all
__global__ void k_sink(const int* __restrict__ cnt, const int* __restrict__ offs,
                       float* __restrict__ q, const int* __restrict__ idx,
                       const float* __restrict__ q_all){
  __shared__ float red[256];
  __shared__ float colf[KP];
  int c = blockIdx.x;
  int nc = cnt[c];
  if (nc == 0) return;
  int n0 = offs[c];
  float* Q = q + (size_t)n0*KP;
  int t = threadIdx.x;
  // gather compact q0 from q_all (hoisted k_qlog output)
  for (int i=t;i<nc;i+=256){
    int n = idx[n0+i];
    #pragma unroll
    for (int k=0;k<KP;k++) Q[(size_t)i*KP + k] = q_all[(size_t)n*KP + k];
  }
  __syncthreads();
  int tot5 = nc*KP;
  float s = 0.f;
  for (int i=t;i<tot5;i+=256) s += Q[i];
  float total = blockSum(s, red);
  float sc = 1.0f/fmaxf(total, 1e-9f);
  for (int i=t;i<tot5;i+=256) Q[i] *= sc;
  __syncthreads();
  float ncf = (float)nc;
  for (int it=0; it<3; it++){
    float cs[KP] = {0,0,0,0,0};
    for (int i=t;i<nc;i+=256){
      const float* row = Q + (size_t)i*KP;
      #pragma unroll
      for (int k=0;k<KP;k++) cs[k] += row[k];
    }
    for (int k=0;k<KP;k++){
      float v = blockSum(cs[k], red);
      if (t==0) colf[k] = 1.0f/(fmaxf(v,1e-9f)*(float)KP);
    }
    __syncthreads();
    for (int i=t;i<nc;i+=256){
      float* row = Q + (size_t)i*KP;
      float qq[KP]; float rs = 0.f;
      #pragma unroll
      for (int k=0;k<KP;k++){ qq[k] = row[k]*colf[k]; rs += qq[k]; }
      float rf = 1.0f/(fmaxf(rs,1e-9f)*ncf);
      #pragma unroll
      for (int k=0;k<KP;k++) row[k] = qq[k]*rf;
    }
    __syncthreads();
  }
  for (int i=t;i<tot5;i+=256) Q[i] *= ncf;
}

// P4[s][c][k][d] partial sums (r16 proven, PSPLIT row-parallel)
__global__ void k_pnew(const int* __restrict__ cnt, const int* __restrict__ offs,
                       const int* __restrict__ present, const int* __restrict__ idx,
                       const float* __restrict__ q, const unsigned short* __restrict__ ptn,
                       float* __restrict__ P4){
  int c = blockIdx.y, s = blockIdx.x;
  if (!present[c]) return;
  int nc = cnt[c], n0 = offs[c];
  int r0 = n0 + (nc*s)/PSPLIT;
  int r1 = n0 + (nc*(s+1))/PSPLIT;
  int t = threadIdx.x;
  float acc[KP][3];
  #pragma unroll
  for (int k=0;k<KP;k++){ acc[k][0]=0.f; acc[k][1]=0.f; acc[k][2]=0.f; }
  for (int i=r0; i<r1; ++i){
    int n = idx[i];
    float qv[KP];
    #pragma unroll
    for (int k=0;k<KP;k++) qv[k] = q[(size_t)i*KP + k];
    const unsigned short* row = ptn + (size_t)n*DIM;
    #pragma unroll
    for (int j=0;j<3;j++){
      float x = bf2f(row[t + j*256]);
      #pragma unroll
      for (int k=0;k<KP;k++) acc[k][j] += qv[k]*x;
    }
  }
  float* out = P4 + ((size_t)(s*NCLS + c)*KP)*DIM;
  #pragma unroll
  for (int k=0;k<KP;k++)
    #pragma unroll
    for (int j=0;j<3;j++)
      out[(size_t)k*DIM + t + j*256] = acc[k][j];
}

// fused: new_prototypes EMA + ipl/class_logits decode
__global__ void k_emafinal(const float* __restrict__ protos, const float* __restrict__ P4,
                           const int* __restrict__ present,
                           const unsigned int* __restrict__ ipl_enc,
                           float* __restrict__ out){
  int bid = blockIdx.x;
  if (bid < 3015){
    int i = bid*256 + threadIdx.x;
    if (i >= NCLS*KP*DIM) return;
    int c = i / (KP*DIM);
    float p = protos[i];
    float* o = out + 32*NCLS + 32*NCLS*KP;
    if (present[c]){
      float s = 0.f;
      #pragma unroll
      for (int sp=0; sp<PSPLIT; sp++) s += P4[(size_t)sp*NCLS*KP*DIM + i];
      o[i] = 0.9f*p + 0.1f*s;
    } else {
      o[i] = p;
    }
  } else {
    int i = (bid-3015)*256 + threadIdx.x;
    if (i < 32*NCLS*KP){
      int b = i / (NCLS*KP), ck = i % (NCLS*KP);
      out[32*NCLS + i] = fdec(ipl_enc[b*CKPAD + ck]);
    }
    if (i < 32*NCLS){
      int b = i / NCLS, c = i % NCLS;
      float s = 0.f;
      #pragma unroll
      for (int k=0;k<KP;k++) s += fdec(ipl_enc[b*CKPAD + c*KP + k]);
      out[b*NCLS + c] = s;
    }
  }
}

// ---------- launch ----------
extern "C" void kernel_launch(void* const* d_in, const int* in_sizes, int n_in,
                              void* d_out, int out_size, void* d_ws, size_t ws_size,
                              hipStream_t stream){
  (void)in_sizes; (void)n_in; (void)out_size; (void)ws_size;
  const float* X = (const float*)d_in[0];
  const float* protos = (const float*)d_in[1];
  const int* labels_raw = (const int*)d_in[2];
  float* out = (float*)d_out;

  char* w = (char*)d_ws;
  size_t off = 0;
  auto alloc = [&](size_t bytes)->void*{
    void* p = (void*)(w + off);
    off = (off + bytes + 255) & ~(size_t)255;
    return p;
  };
  signed char* q1T      = (signed char*)alloc((size_t)DIM*BN_TOT);
  signed char* q2T      = (signed char*)alloc((size_t)DIM*BN_TOT);
  unsigned short* ptn   = (unsigned short*)alloc((size_t)BN_TOT*DIM*2);
  unsigned short* protn = (unsigned short*)alloc((size_t)CKPAD*DIM*2);
  float* q_all   = (float*)alloc((size_t)BN_TOT*KP*4);
  float* Gpart   = (float*)alloc((size_t)GSPLIT*DIM*DIM*4);   // 16 chain1 + 16 chain2
  float* G       = (float*)alloc((size_t)DIM*DIM*4);
  float* meansum = (float*)alloc(DIM*4);
  float* vA      = (float*)alloc(DIM*4);
  float* vB      = (float*)alloc(DIM*4);
  int* cnt       = (int*)alloc(1024);
  int* cur       = (int*)alloc(1024);
  int* offs      = (int*)alloc(1024);
  int* present   = (int*)alloc(1024);
  int* labc      = (int*)alloc(256);
  int* dcnt      = (int*)alloc(256);
  unsigned int* minmax  = (unsigned int*)alloc(256);
  unsigned int* ipl_enc = (unsigned int*)alloc((size_t)32*CKPAD*4);

  // post-gfix buffers alias the (then-dead) Gpart region
  char* gb = (char*)Gpart;
  size_t goff = 0;
  auto galloc = [&](size_t bytes)->void*{
    void* p = (void*)(gb + goff);
    goff = (goff + bytes + 255) & ~(size_t)255;
    return p;
  };
  float* u_  = (float*)galloc(BN_TOT*4);
  int* pl_   = (int*)galloc(BN_TOT*4);
  int* idx_  = (int*)galloc(BN_TOT*4);
  float* q_  = (float*)galloc((size_t)BN_TOT*KP*4);
  float* P4_ = (float*)galloc((size_t)PSPLIT*NCLS*KP*DIM*4);

  dim3 b256(256);
  k_setup<<<dim3(128), b256, 0, stream>>>(ipl_enc, cnt, cur, present, minmax, meansum,
                                          labels_raw, labc, vA, protos, protn, dcnt);
  k_prep<<<dim3(2048), b256, 0, stream>>>(X, ptn, q1T, q2T, meansum, protn, labels_raw, q_all);
  k_mega<<<dim3(NBLK_G + 2048), b256, 0, stream>>>(q1T, q2T, Gpart, ptn, protn, ipl_enc);
  k_gfix<<<dim3(576), b256, 0, stream>>>(Gpart, meansum, G);
  for (int it=0; it<10; it++){
    float* src = (it&1) ? vB : vA;
    float* dst = (it&1) ? vA : vB;
    k_mv<<<dim3(192), b256, 0, stream>>>(G, src, dst);
  }
  k_u<<<dim3(2048), b256, 0, stream>>>(X, vA, meansum, u_, minmax);
  k_pl<<<dim3(128), b256, 0, stream>>>(u_, labc, minmax, pl_, cnt, offs, present, dcnt);
  k_scatter<<<dim3(128), b256, 0, stream>>>(pl_, offs, cur, idx_);
  k_sink<<<dim3(200), b256, 0, stream>>>(cnt, offs, q_, idx_, q_all);
  k_pnew<<<dim3(PSPLIT,NCLS), b256, 0, stream>>>(cnt, offs, present, idx_, q_, ptn, P4_);
  k_emafinal<<<dim3(3141), b256, 0, stream>>>(protos, P4_, present, ipl_enc, out);
}

// Round 21
// 443.291 us; speedup vs baseline: 1.0167x; 1.0167x over previous
//
#include <hip/hip_runtime.h>
#include <stdint.h>
#include <stddef.h>

#define DEV static __device__ __forceinline__

typedef __attribute__((ext_vector_type(8))) short bf16x8;
typedef __attribute__((ext_vector_type(4))) float f32x4;
typedef __attribute__((ext_vector_type(4))) int i32x4;

// ---------- small helpers ----------
DEV float bf2f(unsigned short u){ union{unsigned int i; float f;} v; v.i = ((unsigned int)u)<<16; return v.f; }
DEV unsigned short f2bf(float f){ union{float f; unsigned int i;} v; v.f=f; unsigned int i=v.i;
  return (unsigned short)((i + 0x7FFFu + ((i>>16)&1u)) >> 16); }
DEV unsigned int fenc(float x){ unsigned int i = __float_as_uint(x); return (i & 0x80000000u) ? ~i : (i | 0x80000000u); }
DEV float fdec(unsigned int e){ unsigned int i = (e & 0x80000000u) ? (e & 0x7FFFFFFFu) : ~e; return __uint_as_float(i); }

DEV float waveSum(float s){
  for (int m=32;m;m>>=1) s += __shfl_xor(s, m, 64);
  return s;
}

DEV float blockSum(float v, float* red){
  int t = threadIdx.x;
  red[t] = v; __syncthreads();
  for (int k=128;k>0;k>>=1){ if (t<k) red[t] += red[t+k]; __syncthreads(); }
  float r = red[0]; __syncthreads();
  return r;
}

// async global->LDS, 16B per lane; lds base wave-uniform, dest = base + lane*16
DEV void gl16(const void* g, void* lds){
  __builtin_amdgcn_global_load_lds(
      (const __attribute__((address_space(1))) void*)g,
      (__attribute__((address_space(3))) void*)lds, 16, 0, 0);
}

// XLA ErfInv32 (Giles polynomial, log1p variant)
DEV float erfinv_f(float x){
  float w = -log1pf(-__fmul_rn(x,x));
  float p;
  if (w < 5.0f){
    w = w - 2.5f;
    p = 2.81022636e-08f;
    p = 3.43273939e-07f + p*w;
    p = -3.5233877e-06f + p*w;
    p = -4.39150654e-06f + p*w;
    p = 0.00021858087f + p*w;
    p = -0.00125372503f + p*w;
    p = -0.00417768164f + p*w;
    p = 0.246640727f + p*w;
    p = 1.50140941f + p*w;
  } else {
    w = sqrtf(w) - 3.0f;
    p = -0.000200214257f;
    p = 0.000100950558f + p*w;
    p = 0.00134934322f + p*w;
    p = -0.00367342844f + p*w;
    p = 0.00573950773f + p*w;
    p = -0.0076224613f + p*w;
    p = 0.00943887047f + p*w;
    p = 1.00167406f + p*w;
    p = 2.83297682f + p*w;
  }
  return p*x;
}

// ---------- constants ----------
#define BN_TOT 32768
#define DIM 768
#define NCLS 201
#define KP 5
#define CKPAD 1024
#define NSPLIT_G 16       // K-splits per chain (2 chains -> 32 Gpart slices)
#define GSPLIT 32
#define PSPLIT 8
#define NBLK_G 672        // G12 blocks (2 chains x 336)

// ---------- kernels ----------

// fused setup: init accumulators + labels canonicalize + v0 + proto-normalize
__global__ void k_setup(unsigned int* ipl_enc, int* cnt, int* cur, int* present,
                        unsigned int* minmax, float* meansum,
                        const int* __restrict__ raw, int* __restrict__ lab,
                        float* __restrict__ v,
                        const float* __restrict__ protos, unsigned short* __restrict__ protn,
                        int* __restrict__ dcnt){
  int i = blockIdx.x*256 + threadIdx.x;   // exactly 32768 threads
  ipl_enc[i] = 0u;
  if (i < NCLS){ cnt[i]=0; cur[i]=0; present[i]=0; }
  if (i < DIM) meansum[i] = 0.f;
  if (i == 0){
    minmax[0]=0xFFFFFFFFu; minmax[1]=0u;
    dcnt[0] = 0;
    bool is64 = true;
    for (int j=0;j<8;j++){
      int lo = raw[2*j], hi = raw[2*j+1];
      if (hi != 0 || lo < 0 || lo >= NCLS-1){ is64 = false; break; }
    }
    for (int j=0;j<32;j++) lab[j] = is64 ? raw[2*j] : raw[j];
  }
  if (i < DIM){
    unsigned int ks[3] = {0u, 1u, 0x1BD11BDBu};
    const int rot0[4] = {13,15,26,6};
    const int rot1[4] = {17,29,16,24};
    unsigned int x0 = 0u, x1 = (unsigned int)i;
    x0 += ks[0]; x1 += ks[1];
    #pragma unroll
    for (int g=0; g<5; g++){
      const int* rr = (g&1) ? rot1 : rot0;
      #pragma unroll
      for (int j=0;j<4;j++){
        x0 += x1;
        x1 = (x1 << rr[j]) | (x1 >> (32-rr[j]));
        x1 ^= x0;
      }
      x0 += ks[(g+1)%3];
      x1 += ks[(g+2)%3] + (unsigned int)(g+1);
    }
    unsigned int b = x0 ^ x1;
    const float lo = __uint_as_float(0xBF7FFFFFu);
    const float sq2 = __uint_as_float(0x3FB504F3u);
    float f = __uint_as_float((b>>9) | 0x3F800000u) - 1.0f;
    float uu = __fadd_rn(__fmul_rn(f, 2.0f), lo);
    uu = fmaxf(lo, uu);
    v[i] = sq2 * erfinv_f(uu);
  }
  // proto rows: 8 per block, 2 rows per wave
  int l = threadIdx.x & 63;
  #pragma unroll
  for (int rr=0; rr<2; rr++){
    int row = blockIdx.x*8 + (threadIdx.x>>6)*2 + rr;
    if (row >= NCLS*KP){
      for (int j=0;j<12;j++) protn[(size_t)row*DIM + l + j*64] = 0;
    } else {
      const float* p = protos + (size_t)row*DIM;
      float x[12]; float s = 0.f;
      for (int j=0;j<12;j++){ x[j] = p[l + j*64]; s += x[j]*x[j]; }
      s = waveSum(s);
      float inv = 1.0f / fmaxf(sqrtf(s), 1e-12f);
      for (int j=0;j<12;j++) protn[(size_t)row*DIM + l + j*64] = f2bf(x[j]*inv);
    }
  }
}

// FUSED prep: single pass over X producing ptn, q1T/q2T, meansum (r18 proven).
__global__ __launch_bounds__(256) void k_prep(const float* __restrict__ X,
                                              unsigned short* __restrict__ ptn,
                                              signed char* __restrict__ q1T,
                                              signed char* __restrict__ q2T,
                                              float* __restrict__ meansum){
  __shared__ float tile[16][DIM];
  int bid = blockIdx.x;                 // 2048 blocks
  int xcd = bid & 7, j = bid >> 3;      // j in 0..255
  int n0 = xcd*4096 + j*16;
  int t = threadIdx.x;
  {
    const float4* src = (const float4*)(X + (size_t)n0*DIM);
    float4* dst = (float4*)&tile[0][0];
    #pragma unroll
    for (int i=0;i<12;i++) dst[t + i*256] = src[t + i*256];
  }
  __syncthreads();
  int w = t>>6, l = t&63;
  #pragma unroll
  for (int rr=0; rr<4; rr++){
    int r = w*4 + rr;
    const float4* xr = (const float4*)&tile[r][0];
    float4 x4[3]; float s = 0.f;
    #pragma unroll
    for (int jj=0;jj<3;jj++){
      x4[jj] = xr[l + jj*64];
      s += x4[jj].x*x4[jj].x + x4[jj].y*x4[jj].y + x4[jj].z*x4[jj].z + x4[jj].w*x4[jj].w;
    }
    s = waveSum(s);
    float inv = 1.0f / fmaxf(sqrtf(s), 1e-12f);
    #pragma unroll
    for (int jj=0;jj<3;jj++){
      ushort4 o;
      o.x = f2bf(x4[jj].x*inv); o.y = f2bf(x4[jj].y*inv);
      o.z = f2bf(x4[jj].z*inv); o.w = f2bf(x4[jj].w*inv);
      *(ushort4*)&ptn[(size_t)(n0+r)*DIM + 4*(l + jj*64)] = o;
    }
  }
  #pragma unroll
  for (int cc=0; cc<3; cc++){
    int c = t + cc*256;
    unsigned int u1[4], u2[4];
    #pragma unroll
    for (int g=0; g<4; g++){
      unsigned int p1 = 0, p2 = 0;
      #pragma unroll
      for (int k=0;k<4;k++){
        float xx = tile[g*4+k][c];
        int v1 = (int)rintf(xx*16.0f);
        v1 = max(-127, min(127, v1));
        float r2 = xx - (float)v1*(1.0f/16.0f);
        int v2 = (int)rintf(r2*2048.0f);
        v2 = max(-127, min(127, v2));
        p1 |= ((unsigned int)(v1 & 0xff)) << (8*k);
        p2 |= ((unsigned int)(v2 & 0xff)) << (8*k);
      }
      u1[g] = p1; u2[g] = p2;
    }
    uint4 a; a.x=u1[0]; a.y=u1[1]; a.z=u1[2]; a.w=u1[3];
    uint4 b; b.x=u2[0]; b.y=u2[1]; b.z=u2[2]; b.w=u2[3];
    *(uint4*)&q1T[(size_t)c*BN_TOT + n0] = a;
    *(uint4*)&q2T[(size_t)c*BN_TOT + n0] = b;
    float s = 0.f;
    #pragma unroll
    for (int r=0;r<16;r++) s += tile[r][c];
    atomicAdd(&meansum[c], s);
  }
}

// decode (ib,jb) from upper-tri pair index (128-tiles, 6x6) + XCD-grouped split
DEV void g_coords(int b, int& s, int& ib, int& jb){
  int xcd = b & 7, q = b >> 3;            // per chain: 336 blocks, q in 0..41
  s = xcd + 8*(q/21);                     // K-split 0..15 -> xcd s%8 (L2 reuse)
  int p = q % 21;
  ib = 0; int rem = p;
  while (rem >= 6 - ib){ rem -= 6 - ib; ib++; }
  jb = ib + rem;
}

// MEGA dispatch: three independent GEMM populations co-resident (r17 proven).
__global__ __launch_bounds__(256) void k_mega(const signed char* __restrict__ q1T,
                                              const signed char* __restrict__ q2T,
                                              float* __restrict__ Gpart,
                                              const unsigned short* __restrict__ A,
                                              const unsigned short* __restrict__ Bt,
                                              unsigned int* __restrict__ ipl_enc){
  __shared__ __align__(16) signed char LB[32768];
  __shared__ float red[2][2][64];
  int bid = blockIdx.x;
  int t = threadIdx.x, w = t>>6, l = t&63;
  int wr = w>>1, wc = w&1;

  if (bid < NBLK_G){
    int chain2 = (bid >= 21*NSPLIT_G);
    int s, ib, jb; g_coords(chain2 ? bid - 21*NSPLIT_G : bid, s, ib, jb);
    size_t baseA = (size_t)(ib*128)*BN_TOT;
    size_t baseB = (size_t)(jb*128)*BN_TOT;

    i32x4 acc[4][4];
    #pragma unroll
    for (int m=0;m<4;m++)
      #pragma unroll
      for (int n=0;n<4;n++){ acc[m][n][0]=0; acc[m][n][1]=0; acc[m][n][2]=0; acc[m][n][3]=0; }

    float scale;
    if (!chain2){
      signed char* A1 = LB;
      signed char* B1 = LB + 16384;
      int gu = (l&7) ^ ((l>>3)&7);
      size_t lane_off = (size_t)(l>>3)*BN_TOT + (size_t)gu*16;
      for (int kt=0; kt<16; kt++){
        size_t k0 = (size_t)s*2048 + (size_t)kt*128;
        __syncthreads();
        #pragma unroll
        for (int ci=0; ci<4; ci++){
          int rg = w + ci*4;
          size_t roff = (size_t)(rg*8)*BN_TOT + k0 + lane_off;
          gl16(q1T + baseA + roff, A1 + rg*1024);
          gl16(q1T + baseB + roff, B1 + rg*1024);
        }
        __syncthreads();
        #pragma unroll
        for (int kk=0; kk<2; kk++){
          int physb = (((kk*4) + (l>>4)) ^ (l&7))*16;
          i32x4 b1[4];
          #pragma unroll
          for (int n=0;n<4;n++) b1[n] = *(const i32x4*)&B1[(wc*64 + n*16 + (l&15))*128 + physb];
          #pragma unroll
          for (int m=0;m<4;m++){
            i32x4 a1 = *(const i32x4*)&A1[(wr*64 + m*16 + (l&15))*128 + physb];
            #pragma unroll
            for (int n=0;n<4;n++)
              acc[m][n] = __builtin_amdgcn_mfma_i32_16x16x64_i8(a1, b1[n], acc[m][n], 0,0,0);
          }
        }
      }
      scale = 1.0f/256.0f;
    } else {
      signed char* A1 = LB;
      signed char* A2 = LB + 8192;
      signed char* B1 = LB + 16384;
      signed char* B2 = LB + 24576;
      int gu = (l&3) ^ ((l>>2)&3) ^ (l>>4);
      size_t lane_off = (size_t)(l>>2)*BN_TOT + (size_t)gu*16;
      int physc = (l>>4) ^ (l&3) ^ ((l>>2)&3);
      int rdA = (wr*64 + (l&15))*64 + physc*16;
      int rdB = (wc*64 + (l&15))*64 + physc*16;
      for (int kt=0; kt<32; kt++){
        size_t k0 = (size_t)s*2048 + (size_t)kt*64;
        __syncthreads();
        #pragma unroll
        for (int ci=0; ci<2; ci++){
          int c = w + ci*4;
          size_t roff = (size_t)(c*16)*BN_TOT + k0 + lane_off;
          gl16(q1T + baseA + roff, A1 + c*1024);
          gl16(q2T + baseA + roff, A2 + c*1024);
          gl16(q1T + baseB + roff, B1 + c*1024);
          gl16(q2T + baseB + roff, B2 + c*1024);
        }
        __syncthreads();
        i32x4 b1[4], b2[4];
        #pragma unroll
        for (int n=0;n<4;n++){
          b1[n] = *(const i32x4*)&B1[rdB + n*1024];
          b2[n] = *(const i32x4*)&B2[rdB + n*1024];
        }
        #pragma unroll
        for (int m=0;m<4;m++){
          i32x4 a1 = *(const i32x4*)&A1[rdA + m*1024];
          i32x4 a2 = *(const i32x4*)&A2[rdA + m*1024];
          #pragma unroll
          for (int n=0;n<4;n++){
            acc[m][n] = __builtin_amdgcn_mfma_i32_16x16x64_i8(a1, b2[n], acc[m][n], 0,0,0);
            acc[m][n] = __builtin_amdgcn_mfma_i32_16x16x64_i8(a2, b1[n], acc[m][n], 0,0,0);
          }
        }
      }
      scale = 1.0f/32768.0f;
    }

    int slice = chain2 ? (NSPLIT_G + s) : s;
    float* out = Gpart + (size_t)slice*DIM*DIM;
    #pragma unroll
    for (int m=0;m<4;m++)
      #pragma unroll
      for (int n=0;n<4;n++)
        #pragma unroll
        for (int r=0;r<4;r++){
          int row = ib*128 + wr*64 + m*16 + (l>>4)*4 + r;
          int col = jb*128 + wc*64 + n*16 + (l&15);
          float val = (float)acc[m][n][r]*scale;
          out[(size_t)row*DIM + col] = val;
          if (ib != jb) out[(size_t)col*DIM + row] = val;
        }
  } else {
    unsigned short* As = (unsigned short*)LB;          // 16KB
    unsigned short* Bs = (unsigned short*)(LB + 16384);
    int flat = bid - NBLK_G;                           // 0..2047
    int xcd = flat & 7, j = flat >> 3;
    int mb = xcd*32 + (j>>3);
    int nb = j & 7;

    int gu = (l&7) ^ ((l>>3)&7);
    size_t lane_off = (size_t)(l>>3)*DIM + (size_t)gu*8;    // shorts
    size_t baseA = (size_t)(mb*128)*DIM;
    size_t baseB = (size_t)(nb*128)*DIM;

    f32x4 acc[4][4];
    #pragma unroll
    for (int m=0;m<4;m++)
      #pragma unroll
      for (int n=0;n<4;n++){ acc[m][n][0]=0.f; acc[m][n][1]=0.f; acc[m][n][2]=0.f; acc[m][n][3]=0.f; }

    for (int kt=0; kt<12; kt++){
      size_t k0 = (size_t)kt*64;
      __syncthreads();
      #pragma unroll
      for (int ci=0; ci<4; ci++){
        int rg = w + ci*4;
        size_t roff = (size_t)(rg*8)*DIM + k0 + lane_off;
        gl16(A + baseA + roff, &As[rg*512]);
        gl16(Bt + baseB + roff, &Bs[rg*512]);
      }
      __syncthreads();
      #pragma unroll
      for (int kk=0; kk<2; kk++){
        int physb = (((kk*4) + (l>>4)) ^ (l&7))*8;
        bf16x8 a[4], b[4];
        #pragma unroll
        for (int m=0;m<4;m++) a[m] = *(const bf16x8*)&As[(wr*64 + m*16 + (l&15))*64 + physb];
        #pragma unroll
        for (int n=0;n<4;n++) b[n] = *(const bf16x8*)&Bs[(wc*64 + n*16 + (l&15))*64 + physb];
        #pragma unroll
        for (int m=0;m<4;m++)
          #pragma unroll
          for (int n=0;n<4;n++)
            acc[m][n] = __builtin_amdgcn_mfma_f32_16x16x32_bf16(a[m], b[n], acc[m][n], 0,0,0);
      }
    }
    float vmax[4];
    #pragma unroll
    for (int n=0;n<4;n++){
      float v = -1e30f;
      #pragma unroll
      for (int m=0;m<4;m++)
        #pragma unroll
        for (int r=0;r<4;r++) v = fmaxf(v, acc[m][n][r]);
      v = fmaxf(v, __shfl_xor(v, 16, 64));
      v = fmaxf(v, __shfl_xor(v, 32, 64));
      vmax[n] = v;
    }
    __syncthreads();
    if (l < 16){
      #pragma unroll
      for (int n=0;n<4;n++) red[wc][wr][n*16 + l] = vmax[n];
    }
    __syncthreads();
    if (t < 128){
      int wcc = t>>6, col = t&63;
      float v = fmaxf(red[wcc][0][col], red[wcc][1][col]);
      int gcol = nb*128 + wcc*64 + col;
      if (gcol < NCLS*KP){
        int b = (mb*128) >> 10;
        atomicMax(&ipl_enc[b*CKPAD + gcol], fenc(v));
      }
    }
  }
}

// G' = sum(Gpart slices)/N - mu mu^T  (float4; 32 slices)
__global__ void k_gfix(const float* __restrict__ Gpart, const float* __restrict__ meansum,
                       float* __restrict__ G){
  int i4 = blockIdx.x*256 + threadIdx.x;   // < 147456
  int i = i4*4;
  int r = i/DIM, c = i%DIM;
  float4 s = make_float4(0.f,0.f,0.f,0.f);
  for (int p=0;p<GSPLIT;p++){
    float4 g = *(const float4*)&Gpart[(size_t)p*DIM*DIM + i];
    s.x += g.x; s.y += g.y; s.z += g.z; s.w += g.w;
  }
  const float invN = 1.0f/32768.0f;
  float mr = meansum[r]*invN;
  float4 mc = *(const float4*)&meansum[c];
  float4 o;
  o.x = s.x*invN - mr*mc.x*invN;
  o.y = s.y*invN - mr*mc.y*invN;
  o.z = s.z*invN - mr*mc.z*invN;
  o.w = s.w*invN - mr*mc.w*invN;
  *(float4*)&G[i] = o;
}

// v_out = G * v_in   (one wave per row)
__global__ void k_mv(const float* __restrict__ G, const float* __restrict__ vin,
                     float* __restrict__ vout){
  __shared__ float vs[DIM];
  int t = threadIdx.x;
  for (int i=t;i<DIM;i+=256) vs[i] = vin[i];
  __syncthreads();
  int row = blockIdx.x*4 + (t>>6), l = t&63;
  const float* g = G + (size_t)row*DIM;
  float s = 0.f;
  for (int j=0;j<12;j++) s += g[l + j*64]*vs[l + j*64];
  s = waveSum(s);
  if (l==0) vout[row] = s;
}

// u[row] = X[row,:].v - mu.v ; per-block mu.v; fused global min/max.
__global__ void k_u(const float* __restrict__ X, const float* __restrict__ v,
                    const float* __restrict__ meansum,
                    float* __restrict__ u, unsigned int* __restrict__ minmax){
  __shared__ float vs[DIM];
  __shared__ float red[256];
  __shared__ float smn[4], smx[4];
  int t = threadIdx.x;
  for (int i=t;i<DIM;i+=256) vs[i] = v[i];
  __syncthreads();
  float ps = 0.f;
  for (int i=t;i<DIM;i+=256) ps += meansum[i]*(1.0f/32768.0f)*vs[i];
  float scal = blockSum(ps, red);
  int w = t>>6, l = t&63;
  float mn = 1e30f, mx = -1e30f;
  #pragma unroll
  for (int rr=0; rr<4; rr++){
    int row = blockIdx.x*16 + w*4 + rr;
    const float4* xr = (const float4*)(X + (size_t)row*DIM);
    float s = 0.f;
    #pragma unroll
    for (int j=0;j<3;j++){
      float4 x4 = xr[l + j*64];
      int base = 4*(l + j*64);
      s += x4.x*vs[base] + x4.y*vs[base+1] + x4.z*vs[base+2] + x4.w*vs[base+3];
    }
    s = waveSum(s);
    if (l==0){
      float val = s - scal;
      u[row] = val;
      mn = fminf(mn, val); mx = fmaxf(mx, val);
    }
  }
  if (l==0){ smn[w]=mn; smx[w]=mx; }
  __syncthreads();
  if (t==0){
    for (int k=1;k<4;k++){ mn = fminf(mn, smn[k]); mx = fmaxf(mx, smx[k]); }
    atomicMin(&minmax[0], fenc(mn));
    atomicMax(&minmax[1], fenc(mx));
  }
}

// patch labels + per-class counts + (last block) prefix offsets + present bitmap
__global__ void k_pl(const float* __restrict__ u, const int* __restrict__ labels,
                     const unsigned int* __restrict__ minmax, int* __restrict__ pl,
                     int* __restrict__ cnt, int* __restrict__ offs,
                     int* __restrict__ present, int* __restrict__ dcnt){
  int n = blockIdx.x*256 + threadIdx.x;
  int t = threadIdx.x;
  float umin = fdec(minmax[0]), umax = fdec(minmax[1]);
  float us = (u[n]-umin)/(umax-umin);
  int c = (us < 0.5f) ? labels[n>>10] : (NCLS-1);
  pl[n] = c;
  if (c < NCLS-1) atomicAdd(&cnt[c], 1);
  __threadfence();
  __shared__ int lastblk;
  if (t == 0) lastblk = (atomicAdd(dcnt, 1) == 127) ? 1 : 0;
  __syncthreads();
  if (lastblk){
    __shared__ int sc[256];
    sc[t] = (t < NCLS-1) ? atomicAdd(&cnt[t], 0) : 0;
    __syncthreads();
    for (int d=1; d<256; d<<=1){
      int v = (t >= d) ? sc[t-d] : 0;
      __syncthreads();
      sc[t] += v;
      __syncthreads();
    }
    if (t < NCLS) offs[t] = (t == 0) ? 0 : sc[t-1];
    if (t < 32) atomicOr(&present[labels[t]], 1);
  }
}

__global__ void k_scatter(const int* __restrict__ pl, const int* __restrict__ offs,
                          int* __restrict__ cur, int* __restrict__ idx){
  int n = blockIdx.x*256 + threadIdx.x;
  int c = pl[n];
  if (c < NCLS-1){
    int p = offs[c] + atomicAdd(&cur[c], 1);
    idx[p] = n;
  }
}

// own-class logits -> q0 = exp(L/eps), class-sorted order
__global__ void k_qlog(const int* __restrict__ idx, const int* __restrict__ offs,
                       const int* __restrict__ pl, const unsigned short* __restrict__ ptn,
                       const unsigned short* __restrict__ protn, float* __restrict__ q){
  int i = blockIdx.x*4 + (threadIdx.x>>6);
  int l = threadIdx.x & 63;
  int total = offs[NCLS-1];
  if (i >= total) return;
  int n = idx[i];
  int c = pl[n];
  const unsigned short* pr = ptn + (size_t)n*DIM;
  float x[12];
  for (int j=0;j<12;j++) x[j] = bf2f(pr[l + j*64]);
  for (int k=0;k<KP;k++){
    const unsigned short* wv = protn + (size_t)(c*KP + k)*DIM;
    float s = 0.f;
    for (int j=0;j<12;j++) s += x[j]*bf2f(wv[l + j*64]);
    s = waveSum(s);
    if (l==0) q[(size_t)i*KP + k] = expf(s*20.0f);
  }
}

// per-class sinkhorn in place on its sorted segment (r16 proven)
__global__ void k_sink(const int* __restrict__ cnt, const int* __restrict__ offs,
                       float* __restrict__ q){
  __shared__ float red[256];
  __shared__ float colf[KP];
  int c = blockIdx.x;
  int nc = cnt[c];
  if (nc == 0) return;
  int n0 = offs[c];
  float* Q = q + (size_t)n0*KP;
  int t = threadIdx.x;
  int tot5 = nc*KP;
  float s = 0.f;
  for (int i=t;i<tot5;i+=256) s += Q[i];
  float total = blockSum(s, red);
  float sc = 1.0f/fmaxf(total, 1e-9f);
  for (int i=t;i<tot5;i+=256) Q[i] *= sc;
  __syncthreads();
  float ncf = (float)nc;
  for (int it=0; it<3; it++){
    float cs[KP] = {0,0,0,0,0};
    for (int i=t;i<nc;i+=256){
      const float* row = Q + (size_t)i*KP;
      #pragma unroll
      for (int k=0;k<KP;k++) cs[k] += row[k];
    }
    for (int k=0;k<KP;k++){
      float v = blockSum(cs[k], red);
      if (t==0) colf[k] = 1.0f/(fmaxf(v,1e-9f)*(float)KP);
    }
    __syncthreads();
    for (int i=t;i<nc;i+=256){
      float* row = Q + (size_t)i*KP;
      float qq[KP]; float rs = 0.f;
      #pragma unroll
      for (int k=0;k<KP;k++){ qq[k] = row[k]*colf[k]; rs += qq[k]; }
      float rf = 1.0f/(fmaxf(rs,1e-9f)*ncf);
      #pragma unroll
      for (int k=0;k<KP;k++) row[k] = qq[k]*rf;
    }
    __syncthreads();
  }
  for (int i=t;i<tot5;i+=256) Q[i] *= ncf;
}

// P4[s][c][k][d] partial sums (r16 proven, PSPLIT row-parallel)
__global__ void k_pnew(const int* __restrict__ cnt, const int* __restrict__ offs,
                       const int* __restrict__ present, const int* __restrict__ idx,
                       const float* __restrict__ q, const unsigned short* __restrict__ ptn,
                       float* __restrict__ P4){
  int c = blockIdx.y, s = blockIdx.x;
  if (!present[c]) return;
  int nc = cnt[c], n0 = offs[c];
  int r0 = n0 + (nc*s)/PSPLIT;
  int r1 = n0 + (nc*(s+1))/PSPLIT;
  int t = threadIdx.x;
  float acc[KP][3];
  #pragma unroll
  for (int k=0;k<KP;k++){ acc[k][0]=0.f; acc[k][1]=0.f; acc[k][2]=0.f; }
  for (int i=r0; i<r1; ++i){
    int n = idx[i];
    float qv[KP];
    #pragma unroll
    for (int k=0;k<KP;k++) qv[k] = q[(size_t)i*KP + k];
    const unsigned short* row = ptn + (size_t)n*DIM;
    #pragma unroll
    for (int j=0;j<3;j++){
      float x = bf2f(row[t + j*256]);
      #pragma unroll
      for (int k=0;k<KP;k++) acc[k][j] += qv[k]*x;
    }
  }
  float* out = P4 + ((size_t)(s*NCLS + c)*KP)*DIM;
  #pragma unroll
  for (int k=0;k<KP;k++)
    #pragma unroll
    for (int j=0;j<3;j++)
      out[(size_t)k*DIM + t + j*256] = acc[k][j];
}

// fused: new_prototypes EMA + ipl/class_logits decode
__global__ void k_emafinal(const float* __restrict__ protos, const float* __restrict__ P4,
                           const int* __restrict__ present,
                           const unsigned int* __restrict__ ipl_enc,
                           float* __restrict__ out){
  int bid = blockIdx.x;
  if (bid < 3015){
    int i = bid*256 + threadIdx.x;
    if (i >= NCLS*KP*DIM) return;
    int c = i / (KP*DIM);
    float p = protos[i];
    float* o = out + 32*NCLS + 32*NCLS*KP;
    if (present[c]){
      float s = 0.f;
      #pragma unroll
      for (int sp=0; sp<PSPLIT; sp++) s += P4[(size_t)sp*NCLS*KP*DIM + i];
      o[i] = 0.9f*p + 0.1f*s;
    } else {
      o[i] = p;
    }
  } else {
    int i = (bid-3015)*256 + threadIdx.x;
    if (i < 32*NCLS*KP){
      int b = i / (NCLS*KP), ck = i % (NCLS*KP);
      out[32*NCLS + i] = fdec(ipl_enc[b*CKPAD + ck]);
    }
    if (i < 32*NCLS){
      int b = i / NCLS, c = i % NCLS;
      float s = 0.f;
      #pragma unroll
      for (int k=0;k<KP;k++) s += fdec(ipl_enc[b*CKPAD + c*KP + k]);
      out[b*NCLS + c] = s;
    }
  }
}

// ---------- launch ----------
extern "C" void kernel_launch(void* const* d_in, const int* in_sizes, int n_in,
                              void* d_out, int out_size, void* d_ws, size_t ws_size,
                              hipStream_t stream){
  (void)in_sizes; (void)n_in; (void)out_size; (void)ws_size;
  const float* X = (const float*)d_in[0];
  const float* protos = (const float*)d_in[1];
  const int* labels_raw = (const int*)d_in[2];
  float* out = (float*)d_out;

  char* w = (char*)d_ws;
  size_t off = 0;
  auto alloc = [&](size_t bytes)->void*{
    void* p = (void*)(w + off);
    off = (off + bytes + 255) & ~(size_t)255;
    return p;
  };
  signed char* q1T      = (signed char*)alloc((size_t)DIM*BN_TOT);
  signed char* q2T      = (signed char*)alloc((size_t)DIM*BN_TOT);
  unsigned short* ptn   = (unsigned short*)alloc((size_t)BN_TOT*DIM*2);
  unsigned short* protn = (unsigned short*)alloc((size_t)CKPAD*DIM*2);
  float* Gpart   = (float*)alloc((size_t)GSPLIT*DIM*DIM*4);   // 16 chain1 + 16 chain2
  float* G       = (float*)alloc((size_t)DIM*DIM*4);
  float* meansum = (float*)alloc(DIM*4);
  float* vA      = (float*)alloc(DIM*4);
  float* vB      = (float*)alloc(DIM*4);
  int* cnt       = (int*)alloc(1024);
  int* cur       = (int*)alloc(1024);
  int* offs      = (int*)alloc(1024);
  int* present   = (int*)alloc(1024);
  int* labc      = (int*)alloc(256);
  int* dcnt      = (int*)alloc(256);
  unsigned int* minmax  = (unsigned int*)alloc(256);
  unsigned int* ipl_enc = (unsigned int*)alloc((size_t)32*CKPAD*4);

  // post-gfix buffers alias the (then-dead) Gpart region
  char* gb = (char*)Gpart;
  size_t goff = 0;
  auto galloc = [&](size_t bytes)->void*{
    void* p = (void*)(gb + goff);
    goff = (goff + bytes + 255) & ~(size_t)255;
    return p;
  };
  float* u_  = (float*)galloc(BN_TOT*4);
  int* pl_   = (int*)galloc(BN_TOT*4);
  int* idx_  = (int*)galloc(BN_TOT*4);
  float* q_  = (float*)galloc((size_t)BN_TOT*KP*4);
  float* P4_ = (float*)galloc((size_t)PSPLIT*NCLS*KP*DIM*4);

  dim3 b256(256);
  k_setup<<<dim3(128), b256, 0, stream>>>(ipl_enc, cnt, cur, present, minmax, meansum,
                                          labels_raw, labc, vA, protos, protn, dcnt);
  k_prep<<<dim3(2048), b256, 0, stream>>>(X, ptn, q1T, q2T, meansum);
  k_mega<<<dim3(NBLK_G + 2048), b256, 0, stream>>>(q1T, q2T, Gpart, ptn, protn, ipl_enc);
  k_gfix<<<dim3(576), b256, 0, stream>>>(Gpart, meansum, G);
  for (int it=0; it<10; it++){
    float* src = (it&1) ? vB : vA;
    float* dst = (it&1) ? vA : vB;
    k_mv<<<dim3(192), b256, 0, stream>>>(G, src, dst);
  }
  k_u<<<dim3(2048), b256, 0, stream>>>(X, vA, meansum, u_, minmax);
  k_pl<<<dim3(128), b256, 0, stream>>>(u_, labc, minmax, pl_, cnt, offs, present, dcnt);
  k_scatter<<<dim3(128), b256, 0, stream>>>(pl_, offs, cur, idx_);
  k_qlog<<<dim3(8192), b256, 0, stream>>>(idx_, offs, pl_, ptn, protn, q_);
  k_sink<<<dim3(200), b256, 0, stream>>>(cnt, offs, q_);
  k_pnew<<<dim3(PSPLIT,NCLS), b256, 0, stream>>>(cnt, offs, present, idx_, q_, ptn, P4_);
  k_emafinal<<<dim3(3141), b256, 0, stream>>>(protos, P4_, present, ipl_enc, out);
}